// Round 11
// baseline (342.224 us; speedup 1.0000x reference)
//
#include <hip/hip_runtime.h>
#include <hip/hip_bf16.h>
#include <hip/hip_fp16.h>

// GCN: out = softmax( GCNConv2( relu( GCNConv1(x) ) ) )
// GCNConv(x) = D^-1/2 (A+I) D^-1/2 (x W) + b
//
// Round 18:
//  (a) Fused gather+gemm64: BALANCED STATIC PER-WAVE RANGES. Grid = 1024
//      blocks exactly (4 blk/CU x 8 waves = 8192 resident waves); wave gw
//      owns dsts [gw*N/8192, (gw+1)*N/8192) — 12-13 each (max/ideal 1.07),
//      processed in <=8-dst batches through its private LDS strip
//      (gather -> wave-local MFMA -> store, loop). Kills R15's grid tail
//      (1563 tiles / 1024 slots -> 2nd round at 53% residency) with no
//      atomics and no new sync hazards (work = pure function of ids;
//      R16's dynamic-atomic version diverged across replays).
//  (b) Rest unchanged from R17 (two-dst-per-wave softmax, R11 gather loop,
//      MFMA GEMMs, two-level CSR).
// Requires N <= 2^17. N = 100000 here.

#define K_DIM 128
#define PART_VE 16
#define PART_CHUNK 4096   // 256 threads * 16 edges
#define NB_MAX 128        // bucket array size (N <= 128*1024)
#define LDA 136           // LDS row stride in halfs (128 + 8 pad)

typedef _Float16 half8 __attribute__((ext_vector_type(8)));
typedef float floatx4 __attribute__((ext_vector_type(4)));

// Per-bucket edge counts (bucket = dst >> 10).
__global__ __launch_bounds__(256) void hist_buckets(const int* __restrict__ dst, int E,
                                                    int* __restrict__ bucket_count) {
    __shared__ int h[NB_MAX];
    const int t = threadIdx.x;
    if (t < NB_MAX) h[t] = 0;
    __syncthreads();
    const int e0 = blockIdx.x * PART_CHUNK;
    #pragma unroll
    for (int q = 0; q < PART_VE; ++q) {
        const int e = e0 + q * 256 + t;
        if (e < E) atomicAdd(&h[dst[e] >> 10], 1);
    }
    __syncthreads();
    if (t < NB_MAX && h[t]) atomicAdd(&bucket_count[t], h[t]);
}

// Single-wave exclusive scan of the 128 bucket counts (lane owns 2 buckets).
__global__ __launch_bounds__(64) void scan_buckets(const int* __restrict__ bucket_count,
                                                   int* __restrict__ bucket_base,
                                                   int* __restrict__ bucket_cursor,
                                                   int* __restrict__ rowptr, int N, int E) {
    const int t = threadIdx.x;
    const int v0 = bucket_count[2 * t], v1 = bucket_count[2 * t + 1];
    const int tsum = v0 + v1;
    int inc = tsum;
    #pragma unroll
    for (int off = 1; off < 64; off <<= 1) {
        int u = __shfl_up(inc, off, 64);
        if (t >= off) inc += u;
    }
    const int excl = inc - tsum;
    bucket_base[2 * t] = excl;
    bucket_base[2 * t + 1] = excl + v0;
    bucket_cursor[2 * t] = excl;
    bucket_cursor[2 * t + 1] = excl + v0;
    if (t == 63) bucket_base[NB_MAX] = inc;   // == E
    if (t == 0) rowptr[N] = E;
}

// Partition edges into per-bucket contiguous regions with coalesced writes.
// Packed record: (d & 1023) << 17 | src.
__global__ __launch_bounds__(256) void partition_edges(
    const int* __restrict__ ei, int E,
    int* __restrict__ bucket_cursor, int* __restrict__ packed_out)
{
    __shared__ int stage[PART_CHUNK];
    __shared__ unsigned char bstage[PART_CHUNK];
    __shared__ int hist[NB_MAX], lbase[NB_MAX], gbase[NB_MAX], lcur[NB_MAX];
    const int t = threadIdx.x;
    const int e0 = blockIdx.x * PART_CHUNK;
    if (t < NB_MAX) hist[t] = 0;
    __syncthreads();

    int pk[PART_VE], bk[PART_VE];
    #pragma unroll
    for (int q = 0; q < PART_VE; ++q) {
        const int e = e0 + q * 256 + t;
        bk[q] = -1;
        if (e < E) {
            const int s = ei[e];
            const int d = ei[E + e];
            bk[q] = d >> 10;
            pk[q] = ((d & 1023) << 17) | s;
            atomicAdd(&hist[bk[q]], 1);
        }
    }
    __syncthreads();

    if (t < 64) {
        const int v0 = hist[2 * t], v1 = hist[2 * t + 1];
        const int tsum = v0 + v1;
        int inc = tsum;
        #pragma unroll
        for (int off = 1; off < 64; off <<= 1) {
            int u = __shfl_up(inc, off, 64);
            if (t >= off) inc += u;
        }
        const int excl = inc - tsum;
        lbase[2 * t] = excl;        lbase[2 * t + 1] = excl + v0;
        lcur[2 * t]  = excl;        lcur[2 * t + 1]  = excl + v0;
        gbase[2 * t]     = v0 ? atomicAdd(&bucket_cursor[2 * t], v0) : 0;
        gbase[2 * t + 1] = v1 ? atomicAdd(&bucket_cursor[2 * t + 1], v1) : 0;
    }
    __syncthreads();

    #pragma unroll
    for (int q = 0; q < PART_VE; ++q) {
        if (bk[q] >= 0) {
            const int p = atomicAdd(&lcur[bk[q]], 1);
            stage[p]  = pk[q];
            bstage[p] = (unsigned char)bk[q];
        }
    }
    __syncthreads();

    const int total = (E - e0 < PART_CHUNK) ? (E - e0) : PART_CHUNK;
    for (int i = t; i < total; i += 256) {
        const int b = bstage[i];
        packed_out[gbase[b] + (i - lbase[b])] = stage[i];
    }
}

// One block per 1024-node bucket: local histogram -> local scan -> rowptr/norm
// -> LDS-cursor scatter into this bucket's contiguous csr segment.
__global__ __launch_bounds__(1024) void build_csr(
    const int* __restrict__ packed, const int* __restrict__ bucket_base,
    int N, int* __restrict__ rowptr, float* __restrict__ normv,
    int* __restrict__ csr)
{
    __shared__ int ldeg[1024];
    __shared__ int lrow[1024];
    __shared__ int wtot[16];
    const int b = blockIdx.x;
    const int node0 = b << 10;
    const int t = threadIdx.x;
    const int jb = bucket_base[b], je = bucket_base[b + 1];

    ldeg[t] = 0;
    __syncthreads();
    for (int j = jb + t; j < je; j += 1024)
        atomicAdd(&ldeg[packed[j] >> 17], 1);
    __syncthreads();

    const int lane = t & 63, wid = t >> 6;
    const int v = ldeg[t];
    int inc = v;
    #pragma unroll
    for (int off = 1; off < 64; off <<= 1) {
        int u = __shfl_up(inc, off, 64);
        if (lane >= off) inc += u;
    }
    if (lane == 63) wtot[wid] = inc;
    __syncthreads();
    int woff = 0;
    for (int w = 0; w < wid; ++w) woff += wtot[w];
    const int excl = woff + inc - v;
    lrow[t] = excl;
    __syncthreads();

    const int nloc = (N - node0 < 1024) ? (N - node0) : 1024;
    if (t < nloc) {
        rowptr[node0 + t] = jb + excl;
        normv[node0 + t] = rsqrtf((float)(v + 1));   // +1 self-loop
    }
    __syncthreads();

    for (int j = jb + t; j < je; j += 1024) {
        const int pv = packed[j];
        const int slot = jb + atomicAdd(&lrow[pv >> 17], 1);
        csr[slot] = pv & 0x1FFFF;
    }
}

// Transpose-convert weights for MFMA B-operand: W1h[n][k] = (half)W1[k][n],
// W2h[n][k] = (half)W2[k][n]. 16384 + 8192 elems; one tiny kernel.
__global__ __launch_bounds__(256) void prep_weights(
    const float* __restrict__ W1, const float* __restrict__ W2,
    __half* __restrict__ W1h, __half* __restrict__ W2h)
{
    const int idx = blockIdx.x * 256 + threadIdx.x;
    if (idx < 128 * 128) {
        const int n = idx >> 7, k = idx & 127;
        W1h[idx] = __float2half(W1[k * 128 + n]);
    }
    const int idx2 = idx - 128 * 128;
    if (idx2 >= 0 && idx2 < 64 * 128) {
        const int n = idx2 >> 7, k = idx2 & 127;
        W2h[idx2] = __float2half(W2[k * 64 + n]);
    }
}

// Layer-1 MFMA GEMM: H'[row,0..127] = norm[row]*(x[row,:]@W1), fp16 out.
// Split-A (x = hi + lo) so only W-fp16 quantization enters the result.
// 256 thr = 4 waves; wave w owns rows w*16..+15, all 8 col-tiles.
__global__ __launch_bounds__(256) void gemm128_mfma(
    const float* __restrict__ A, const __half* __restrict__ Wh,  // [n][k]
    const float* __restrict__ norm, __half* __restrict__ Hout, int nrows)
{
    __shared__ _Float16 Ah[64 * LDA];
    __shared__ _Float16 Al[64 * LDA];
    __shared__ _Float16 Bh[128 * LDA];
    const int t = threadIdx.x;
    const int row0 = blockIdx.x * 64;

    {   // stage A split hi/lo: thread t -> row t>>2, 32-col segment (t&3)*32
        const int r = t >> 2;
        const int seg = (t & 3) * 32;
        int grow = row0 + r;
        if (grow > nrows - 1) grow = nrows - 1;
        const float* src = &A[(size_t)grow * K_DIM + seg];
        _Float16 hi[32], lo[32];
        #pragma unroll
        for (int i = 0; i < 8; ++i) {
            float4 v = *(const float4*)&src[i * 4];
            const float vf[4] = {v.x, v.y, v.z, v.w};
            #pragma unroll
            for (int j = 0; j < 4; ++j) {
                _Float16 h = (_Float16)vf[j];
                hi[i * 4 + j] = h;
                lo[i * 4 + j] = (_Float16)(vf[j] - (float)h);
            }
        }
        #pragma unroll
        for (int c = 0; c < 4; ++c) {
            *(half8*)&Ah[r * LDA + seg + c * 8] = *(half8*)&hi[c * 8];
            *(half8*)&Al[r * LDA + seg + c * 8] = *(half8*)&lo[c * 8];
        }
    }
    {   // stage B: 128x128 halfs = 2048 b128-chunks, 8 per thread
        const _Float16* wf = (const _Float16*)Wh;
        #pragma unroll
        for (int i = 0; i < 8; ++i) {
            const int id = i * 256 + t;
            const int n = id >> 4, kc = id & 15;
            *(half8*)&Bh[n * LDA + kc * 8] = *(const half8*)&wf[n * 128 + kc * 8];
        }
    }
    __syncthreads();

    const int lane = t & 63, wave = t >> 6;
    const int m = lane & 15, quad = lane >> 4;
    const int arow = wave * 16 + m;

    floatx4 acc[8];
    #pragma unroll
    for (int nt = 0; nt < 8; ++nt) acc[nt] = (floatx4){0.f, 0.f, 0.f, 0.f};

    #pragma unroll
    for (int k0 = 0; k0 < 128; k0 += 32) {
        half8 ah = *(const half8*)&Ah[arow * LDA + k0 + quad * 8];
        half8 al = *(const half8*)&Al[arow * LDA + k0 + quad * 8];
        #pragma unroll
        for (int nt = 0; nt < 8; ++nt) {
            half8 b = *(const half8*)&Bh[(nt * 16 + m) * LDA + k0 + quad * 8];
            acc[nt] = __builtin_amdgcn_mfma_f32_16x16x32_f16(ah, b, acc[nt], 0, 0, 0);
            acc[nt] = __builtin_amdgcn_mfma_f32_16x16x32_f16(al, b, acc[nt], 0, 0, 0);
        }
    }

    // D: row = quad*4 + reg, col = nt*16 + m
    #pragma unroll
    for (int reg = 0; reg < 4; ++reg) {
        const int row = row0 + wave * 16 + quad * 4 + reg;
        if (row < nrows) {
            const float nr = norm[row];
            #pragma unroll
            for (int nt = 0; nt < 8; ++nt)
                Hout[(size_t)row * 128 + nt * 16 + m] = __float2half(acc[nt][reg] * nr);
        }
    }
}

// Fused layer-1 aggregation + layer-2 GEMM, balanced static per-wave ranges.
// Grid = 1024 blocks x 512 thr (8192 waves, full residency). Wave gw owns
// dsts [gw*n/8192, (gw+1)*n/8192) — 12-13 dsts — processed in <=8-dst
// batches: gather batch into own LDS strip (R11 inner loop) -> wave-local
// MFMA (A rows >= cnt are stale/neighbor garbage; D row r depends only on
// A row r, so garbage stays in unstored D rows) -> store cnt h2' rows.
// Deterministic (work = pure function of ids), no atomics, one barrier (W2).
__global__ __launch_bounds__(512, 8) void gather_relu_gemm64(
    const int* __restrict__ rowptr, const int* __restrict__ csr,
    const float* __restrict__ norm, const __half* __restrict__ h,
    const float* __restrict__ bias, const __half* __restrict__ W2h,
    __half* __restrict__ h2, int n)
{
    __shared__ _Float16 Ah[72 * LDA];   // 64 data rows + 8 pad (wave 7 A-read overrun)
    __shared__ _Float16 Bh[64 * LDA];
    const int t = threadIdx.x;
    const int lane = t & 63, wave = t >> 6;
    const __half2* hp = (const __half2*)h;   // row stride 64 half2 (256 B)

    {   // stage W2 [64][128] halfs = 1024 b128-chunks, 2 per thread
        const _Float16* wf = (const _Float16*)W2h;
        #pragma unroll
        for (int i = 0; i < 2; ++i) {
            const int id = i * 512 + t;
            const int nn = id >> 4, kc = id & 15;
            *(half8*)&Bh[nn * LDA + kc * 8] = *(const half8*)&wf[nn * 128 + kc * 8];
        }
    }
    __syncthreads();   // only barrier: Bh ready for all waves

    const float bx = bias[2 * lane], by = bias[2 * lane + 1];
    const int m = lane & 15, quad = lane >> 4;

    const int gw = blockIdx.x * 8 + wave;                       // 0..8191
    const int start = (int)(((long long)gw * n) >> 13);         // gw*n/8192
    const int end   = (int)(((long long)(gw + 1) * n) >> 13);

    for (int d0 = start; d0 < end; d0 += 8) {
        const int cnt = (end - d0 < 8) ? (end - d0) : 8;

        for (int i = 0; i < cnt; ++i) {
            const int d = __builtin_amdgcn_readfirstlane(d0 + i);
            const int jb = rowptr[d], je = rowptr[d + 1];
            float ax[8] = {}, ay[8] = {};
            int j = jb;
            if (j + 8 <= je) {
                int s[8];
                #pragma unroll
                for (int q = 0; q < 8; ++q) s[q] = csr[j + q];
                for (; j + 16 <= je; j += 8) {
                    int sn[8];
                    #pragma unroll
                    for (int q = 0; q < 8; ++q) sn[q] = csr[j + 8 + q];
                    #pragma unroll
                    for (int q = 0; q < 8; ++q) {
                        const float2 v = __half22float2(hp[(size_t)s[q] * 64 + lane]);
                        ax[q] += v.x; ay[q] += v.y;
                    }
                    #pragma unroll
                    for (int q = 0; q < 8; ++q) s[q] = sn[q];
                }
                #pragma unroll
                for (int q = 0; q < 8; ++q) {
                    const float2 v = __half22float2(hp[(size_t)s[q] * 64 + lane]);
                    ax[q] += v.x; ay[q] += v.y;
                }
                j += 8;
            }
            for (; j < je; ++j) {
                const float2 v = __half22float2(hp[(size_t)csr[j] * 64 + lane]);
                ax[0] += v.x; ay[0] += v.y;
            }

            const float2 sv = __half22float2(hp[(size_t)d * 64 + lane]);  // self (premult)
            const float nd = norm[d];
            float sx = ((ax[0] + ax[1]) + (ax[2] + ax[3])) + ((ax[4] + ax[5]) + (ax[6] + ax[7])) + sv.x;
            float sy = ((ay[0] + ay[1]) + (ay[2] + ay[3])) + ((ay[4] + ay[5]) + (ay[6] + ay[7])) + sv.y;
            const float ox = fmaxf(fmaf(nd, sx, bx), 0.f);
            const float oy = fmaxf(fmaf(nd, sy, by), 0.f);
            ((__half2*)Ah)[((wave << 3) + i) * (LDA / 2) + lane] = __floats2half2_rn(ox, oy);
        }

        // Wave-local gemm: D rows 0..cnt-1 valid, rest garbage (discarded).
        const int arow = (wave << 3) + m;   // m >= cnt reads stale/neighbor strip

        floatx4 acc[4];
        #pragma unroll
        for (int nt = 0; nt < 4; ++nt) acc[nt] = (floatx4){0.f, 0.f, 0.f, 0.f};

        #pragma unroll
        for (int k0 = 0; k0 < 128; k0 += 32) {
            half8 ah = *(const half8*)&Ah[arow * LDA + k0 + quad * 8];
            #pragma unroll
            for (int nt = 0; nt < 4; ++nt) {
                half8 b = *(const half8*)&Bh[(nt * 16 + m) * LDA + k0 + quad * 8];
                acc[nt] = __builtin_amdgcn_mfma_f32_16x16x32_f16(ah, b, acc[nt], 0, 0, 0);
            }
        }

        // D: row = quad*4 + reg (keep < cnt), col = nt*16 + m
        #pragma unroll
        for (int reg = 0; reg < 4; ++reg) {
            const int rl = quad * 4 + reg;
            if (rl < cnt) {
                const int row = d0 + rl;
                const float nr = norm[row];
                #pragma unroll
                for (int nt = 0; nt < 4; ++nt)
                    h2[(size_t)row * 64 + nt * 16 + m] = __float2half(acc[nt][reg] * nr);
            }
        }
    }
}

// Layer-2 aggregation + row softmax, TWO DSTS PER WAVE: half-wave hw owns
// dst 2p+hw; its 32 lanes read the 128 B h2 row as half2 (one wave-instr
// covers both half-waves' rows = 256 B, 8-deep = 2 KB in flight vs 1 KB for
// the old scalar-fp16 form). Reductions via __shfl_xor offsets <=16 stay
// within each 32-lane half. Output: coalesced float2 (256 B per dst).
__global__ __launch_bounds__(256) void gather_softmax(
    const int* __restrict__ rowptr, const int* __restrict__ csr,
    const float* __restrict__ norm, const __half* __restrict__ h,
    const float* __restrict__ bias, float* __restrict__ out, int n)
{
    const int t = threadIdx.x;
    const int lane = t & 63;
    const int cl = lane & 31;                               // half2 col 0..31
    const int d = blockIdx.x * 8 + ((t >> 6) << 1) + (lane >> 5);
    if (d >= n) return;
    const __half2* hp = (const __half2*)h;                  // row stride 32 half2 (128 B)

    const int jb = rowptr[d], je = rowptr[d + 1];
    float ax[8] = {}, ay[8] = {};
    int j = jb;
    if (j + 8 <= je) {
        int s[8];
        #pragma unroll
        for (int q = 0; q < 8; ++q) s[q] = csr[j + q];
        for (; j + 16 <= je; j += 8) {
            int sn[8];
            #pragma unroll
            for (int q = 0; q < 8; ++q) sn[q] = csr[j + 8 + q];
            #pragma unroll
            for (int q = 0; q < 8; ++q) {
                const float2 v = __half22float2(hp[(size_t)s[q] * 32 + cl]);
                ax[q] += v.x; ay[q] += v.y;
            }
            #pragma unroll
            for (int q = 0; q < 8; ++q) s[q] = sn[q];
        }
        #pragma unroll
        for (int q = 0; q < 8; ++q) {
            const float2 v = __half22float2(hp[(size_t)s[q] * 32 + cl]);
            ax[q] += v.x; ay[q] += v.y;
        }
        j += 8;
    }
    for (; j < je; ++j) {
        const float2 v = __half22float2(hp[(size_t)csr[j] * 32 + cl]);
        ax[0] += v.x; ay[0] += v.y;
    }

    const float2 sv = __half22float2(hp[(size_t)d * 32 + cl]);   // self (premult)
    const float nd = norm[d];
    float sx = ((ax[0] + ax[1]) + (ax[2] + ax[3])) + ((ax[4] + ax[5]) + (ax[6] + ax[7])) + sv.x;
    float sy = ((ay[0] + ay[1]) + (ay[2] + ay[3])) + ((ay[4] + ay[5]) + (ay[6] + ay[7])) + sv.y;
    const float a_x = fmaf(nd, sx, bias[2 * cl]);
    const float a_y = fmaf(nd, sy, bias[2 * cl + 1]);

    float m = fmaxf(a_x, a_y);
    #pragma unroll
    for (int off = 16; off; off >>= 1) m = fmaxf(m, __shfl_xor(m, off, 64));
    const float ex = expf(a_x - m), ey = expf(a_y - m);
    float ss = ex + ey;
    #pragma unroll
    for (int off = 16; off; off >>= 1) ss += __shfl_xor(ss, off, 64);
    const float inv = 1.f / ss;
    float2 o2; o2.x = ex * inv; o2.y = ey * inv;
    *(float2*)&out[(size_t)d * 64 + 2 * cl] = o2;
}

extern "C" void kernel_launch(void* const* d_in, const int* in_sizes, int n_in,
                              void* d_out, int out_size, void* d_ws, size_t ws_size,
                              hipStream_t stream) {
    const float* x  = (const float*)d_in[0];
    const int*   ei = (const int*)d_in[1];
    const float* W1 = (const float*)d_in[2];
    const float* b1 = (const float*)d_in[3];
    const float* W2 = (const float*)d_in[4];
    const float* b2 = (const float*)d_in[5];
    float* out = (float*)d_out;

    const int N = in_sizes[0] / K_DIM;     // 100000 (<= 2^17 required)
    const int E = in_sizes[1] / 2;         // 1600000
    const int NBUCK = (N + 1023) >> 10;    // 98 buckets of 1024 nodes

    // Workspace layout (peak ~65 MB)
    size_t o = 0;
    char* base = (char*)d_ws;
    auto alloc = [&](size_t elems) {       // elems in 4-byte units
        void* p = base + o;
        o += (elems * 4 + 1023) & ~(size_t)1023;
        return p;
    };
    int*    bcount = (int*)   alloc(NB_MAX);
    int*    bbase  = (int*)   alloc(NB_MAX + 1);
    int*    bcur   = (int*)   alloc(NB_MAX);
    int*    rowptr = (int*)   alloc(N + 1);
    float*  norm   = (float*) alloc(N);
    int*    packed = (int*)   alloc(E);
    int*    csr    = (int*)   alloc(E);
    __half* W1h    = (__half*)alloc(128 * 128 / 2);
    __half* W2h    = (__half*)alloc(64 * 128 / 2);
    __half* h1h    = (__half*)alloc((size_t)N * 64);  // fp16 [Nx128]
    __half* h2h    = (__half*)alloc((size_t)N * 32);  // fp16 [Nx64]

    const int nb_c = (E + PART_CHUNK - 1) / PART_CHUNK;   // partition chunks
    const int nb_g2 = (N + 7) / 8;                        // softmax: 8 dsts/block
    const int nb_m = (N + 63) / 64;

    // ---- CSR build (two-level partition) + weight prep ----
    hipMemsetAsync(bcount, 0, NB_MAX * sizeof(int), stream);
    prep_weights<<<96, 256, 0, stream>>>(W1, W2, W1h, W2h);
    hist_buckets<<<nb_c, 256, 0, stream>>>(ei + E, E, bcount);
    scan_buckets<<<1, 64, 0, stream>>>(bcount, bbase, bcur, rowptr, N, E);
    partition_edges<<<nb_c, 256, 0, stream>>>(ei, E, bcur, packed);
    build_csr<<<NBUCK, 1024, 0, stream>>>(packed, bbase, N, rowptr, norm, csr);

    // ---- Layer 1: h1' = norm .* (x@W1), fp16 [N x 128], MFMA split-A ----
    gemm128_mfma<<<nb_m, 256, 0, stream>>>(x, W1h, norm, h1h, N);

    // ---- Fused: agg1 = relu(gather(h1')) in LDS; h2' = norm .* (agg1@W2) ----
    gather_relu_gemm64<<<1024, 512, 0, stream>>>(rowptr, csr, norm, h1h, b1, W2h, h2h, N);

    // ---- Layer 2 aggregation + softmax ----
    gather_softmax<<<nb_g2, 256, 0, stream>>>(rowptr, csr, norm, h2h, b2, out, N);
}

// Round 12
// 284.987 us; speedup vs baseline: 1.2008x; 1.2008x over previous
//
#include <hip/hip_runtime.h>
#include <hip/hip_bf16.h>
#include <hip/hip_fp16.h>

// GCN: out = softmax( GCNConv2( relu( GCNConv1(x) ) ) )
// GCNConv(x) = D^-1/2 (A+I) D^-1/2 (x W) + b
//
// Round 19:
//  (a) R18's balanced static per-wave ranges KEPT (occupancy 58->78%, raw BW
//      3.95 TB/s — the tail fix worked) but its regression fixed: R18's
//      FETCH/WRITE ballooned +126/+115 MB (write side 10x the 12.8 MB h2
//      output) — scratch spill-fill round-tripping to HBM. The trip-2 batch
//      loop was unrolled + software-pipelined by the compiler, overlapping
//      batch k+1's gather arrays (~32 VGPR) with batch k's MFMA acc (16
//      VGPR) past the 64-VGPR cap of launch_bounds(512,8).
//      Fix: #pragma unroll 1 on the batch and per-dst loops + 
//      __builtin_amdgcn_sched_barrier(0) at gather->MFMA and MFMA->store
//      boundaries, so peak pressure = max(phase), not sum.
//  (b) Rest unchanged from R17 (two-dst-per-wave softmax, R11 gather loop,
//      MFMA GEMMs, two-level CSR).
// Requires N <= 2^17. N = 100000 here.

#define K_DIM 128
#define PART_VE 16
#define PART_CHUNK 4096   // 256 threads * 16 edges
#define NB_MAX 128        // bucket array size (N <= 128*1024)
#define LDA 136           // LDS row stride in halfs (128 + 8 pad)

typedef _Float16 half8 __attribute__((ext_vector_type(8)));
typedef float floatx4 __attribute__((ext_vector_type(4)));

// Per-bucket edge counts (bucket = dst >> 10).
__global__ __launch_bounds__(256) void hist_buckets(const int* __restrict__ dst, int E,
                                                    int* __restrict__ bucket_count) {
    __shared__ int h[NB_MAX];
    const int t = threadIdx.x;
    if (t < NB_MAX) h[t] = 0;
    __syncthreads();
    const int e0 = blockIdx.x * PART_CHUNK;
    #pragma unroll
    for (int q = 0; q < PART_VE; ++q) {
        const int e = e0 + q * 256 + t;
        if (e < E) atomicAdd(&h[dst[e] >> 10], 1);
    }
    __syncthreads();
    if (t < NB_MAX && h[t]) atomicAdd(&bucket_count[t], h[t]);
}

// Single-wave exclusive scan of the 128 bucket counts (lane owns 2 buckets).
__global__ __launch_bounds__(64) void scan_buckets(const int* __restrict__ bucket_count,
                                                   int* __restrict__ bucket_base,
                                                   int* __restrict__ bucket_cursor,
                                                   int* __restrict__ rowptr, int N, int E) {
    const int t = threadIdx.x;
    const int v0 = bucket_count[2 * t], v1 = bucket_count[2 * t + 1];
    const int tsum = v0 + v1;
    int inc = tsum;
    #pragma unroll
    for (int off = 1; off < 64; off <<= 1) {
        int u = __shfl_up(inc, off, 64);
        if (t >= off) inc += u;
    }
    const int excl = inc - tsum;
    bucket_base[2 * t] = excl;
    bucket_base[2 * t + 1] = excl + v0;
    bucket_cursor[2 * t] = excl;
    bucket_cursor[2 * t + 1] = excl + v0;
    if (t == 63) bucket_base[NB_MAX] = inc;   // == E
    if (t == 0) rowptr[N] = E;
}

// Partition edges into per-bucket contiguous regions with coalesced writes.
// Packed record: (d & 1023) << 17 | src.
__global__ __launch_bounds__(256) void partition_edges(
    const int* __restrict__ ei, int E,
    int* __restrict__ bucket_cursor, int* __restrict__ packed_out)
{
    __shared__ int stage[PART_CHUNK];
    __shared__ unsigned char bstage[PART_CHUNK];
    __shared__ int hist[NB_MAX], lbase[NB_MAX], gbase[NB_MAX], lcur[NB_MAX];
    const int t = threadIdx.x;
    const int e0 = blockIdx.x * PART_CHUNK;
    if (t < NB_MAX) hist[t] = 0;
    __syncthreads();

    int pk[PART_VE], bk[PART_VE];
    #pragma unroll
    for (int q = 0; q < PART_VE; ++q) {
        const int e = e0 + q * 256 + t;
        bk[q] = -1;
        if (e < E) {
            const int s = ei[e];
            const int d = ei[E + e];
            bk[q] = d >> 10;
            pk[q] = ((d & 1023) << 17) | s;
            atomicAdd(&hist[bk[q]], 1);
        }
    }
    __syncthreads();

    if (t < 64) {
        const int v0 = hist[2 * t], v1 = hist[2 * t + 1];
        const int tsum = v0 + v1;
        int inc = tsum;
        #pragma unroll
        for (int off = 1; off < 64; off <<= 1) {
            int u = __shfl_up(inc, off, 64);
            if (t >= off) inc += u;
        }
        const int excl = inc - tsum;
        lbase[2 * t] = excl;        lbase[2 * t + 1] = excl + v0;
        lcur[2 * t]  = excl;        lcur[2 * t + 1]  = excl + v0;
        gbase[2 * t]     = v0 ? atomicAdd(&bucket_cursor[2 * t], v0) : 0;
        gbase[2 * t + 1] = v1 ? atomicAdd(&bucket_cursor[2 * t + 1], v1) : 0;
    }
    __syncthreads();

    #pragma unroll
    for (int q = 0; q < PART_VE; ++q) {
        if (bk[q] >= 0) {
            const int p = atomicAdd(&lcur[bk[q]], 1);
            stage[p]  = pk[q];
            bstage[p] = (unsigned char)bk[q];
        }
    }
    __syncthreads();

    const int total = (E - e0 < PART_CHUNK) ? (E - e0) : PART_CHUNK;
    for (int i = t; i < total; i += 256) {
        const int b = bstage[i];
        packed_out[gbase[b] + (i - lbase[b])] = stage[i];
    }
}

// One block per 1024-node bucket: local histogram -> local scan -> rowptr/norm
// -> LDS-cursor scatter into this bucket's contiguous csr segment.
__global__ __launch_bounds__(1024) void build_csr(
    const int* __restrict__ packed, const int* __restrict__ bucket_base,
    int N, int* __restrict__ rowptr, float* __restrict__ normv,
    int* __restrict__ csr)
{
    __shared__ int ldeg[1024];
    __shared__ int lrow[1024];
    __shared__ int wtot[16];
    const int b = blockIdx.x;
    const int node0 = b << 10;
    const int t = threadIdx.x;
    const int jb = bucket_base[b], je = bucket_base[b + 1];

    ldeg[t] = 0;
    __syncthreads();
    for (int j = jb + t; j < je; j += 1024)
        atomicAdd(&ldeg[packed[j] >> 17], 1);
    __syncthreads();

    const int lane = t & 63, wid = t >> 6;
    const int v = ldeg[t];
    int inc = v;
    #pragma unroll
    for (int off = 1; off < 64; off <<= 1) {
        int u = __shfl_up(inc, off, 64);
        if (lane >= off) inc += u;
    }
    if (lane == 63) wtot[wid] = inc;
    __syncthreads();
    int woff = 0;
    for (int w = 0; w < wid; ++w) woff += wtot[w];
    const int excl = woff + inc - v;
    lrow[t] = excl;
    __syncthreads();

    const int nloc = (N - node0 < 1024) ? (N - node0) : 1024;
    if (t < nloc) {
        rowptr[node0 + t] = jb + excl;
        normv[node0 + t] = rsqrtf((float)(v + 1));   // +1 self-loop
    }
    __syncthreads();

    for (int j = jb + t; j < je; j += 1024) {
        const int pv = packed[j];
        const int slot = jb + atomicAdd(&lrow[pv >> 17], 1);
        csr[slot] = pv & 0x1FFFF;
    }
}

// Transpose-convert weights for MFMA B-operand: W1h[n][k] = (half)W1[k][n],
// W2h[n][k] = (half)W2[k][n]. 16384 + 8192 elems; one tiny kernel.
__global__ __launch_bounds__(256) void prep_weights(
    const float* __restrict__ W1, const float* __restrict__ W2,
    __half* __restrict__ W1h, __half* __restrict__ W2h)
{
    const int idx = blockIdx.x * 256 + threadIdx.x;
    if (idx < 128 * 128) {
        const int n = idx >> 7, k = idx & 127;
        W1h[idx] = __float2half(W1[k * 128 + n]);
    }
    const int idx2 = idx - 128 * 128;
    if (idx2 >= 0 && idx2 < 64 * 128) {
        const int n = idx2 >> 7, k = idx2 & 127;
        W2h[idx2] = __float2half(W2[k * 64 + n]);
    }
}

// Layer-1 MFMA GEMM: H'[row,0..127] = norm[row]*(x[row,:]@W1), fp16 out.
// Split-A (x = hi + lo) so only W-fp16 quantization enters the result.
// 256 thr = 4 waves; wave w owns rows w*16..+15, all 8 col-tiles.
__global__ __launch_bounds__(256) void gemm128_mfma(
    const float* __restrict__ A, const __half* __restrict__ Wh,  // [n][k]
    const float* __restrict__ norm, __half* __restrict__ Hout, int nrows)
{
    __shared__ _Float16 Ah[64 * LDA];
    __shared__ _Float16 Al[64 * LDA];
    __shared__ _Float16 Bh[128 * LDA];
    const int t = threadIdx.x;
    const int row0 = blockIdx.x * 64;

    {   // stage A split hi/lo: thread t -> row t>>2, 32-col segment (t&3)*32
        const int r = t >> 2;
        const int seg = (t & 3) * 32;
        int grow = row0 + r;
        if (grow > nrows - 1) grow = nrows - 1;
        const float* src = &A[(size_t)grow * K_DIM + seg];
        _Float16 hi[32], lo[32];
        #pragma unroll
        for (int i = 0; i < 8; ++i) {
            float4 v = *(const float4*)&src[i * 4];
            const float vf[4] = {v.x, v.y, v.z, v.w};
            #pragma unroll
            for (int j = 0; j < 4; ++j) {
                _Float16 h = (_Float16)vf[j];
                hi[i * 4 + j] = h;
                lo[i * 4 + j] = (_Float16)(vf[j] - (float)h);
            }
        }
        #pragma unroll
        for (int c = 0; c < 4; ++c) {
            *(half8*)&Ah[r * LDA + seg + c * 8] = *(half8*)&hi[c * 8];
            *(half8*)&Al[r * LDA + seg + c * 8] = *(half8*)&lo[c * 8];
        }
    }
    {   // stage B: 128x128 halfs = 2048 b128-chunks, 8 per thread
        const _Float16* wf = (const _Float16*)Wh;
        #pragma unroll
        for (int i = 0; i < 8; ++i) {
            const int id = i * 256 + t;
            const int n = id >> 4, kc = id & 15;
            *(half8*)&Bh[n * LDA + kc * 8] = *(const half8*)&wf[n * 128 + kc * 8];
        }
    }
    __syncthreads();

    const int lane = t & 63, wave = t >> 6;
    const int m = lane & 15, quad = lane >> 4;
    const int arow = wave * 16 + m;

    floatx4 acc[8];
    #pragma unroll
    for (int nt = 0; nt < 8; ++nt) acc[nt] = (floatx4){0.f, 0.f, 0.f, 0.f};

    #pragma unroll
    for (int k0 = 0; k0 < 128; k0 += 32) {
        half8 ah = *(const half8*)&Ah[arow * LDA + k0 + quad * 8];
        half8 al = *(const half8*)&Al[arow * LDA + k0 + quad * 8];
        #pragma unroll
        for (int nt = 0; nt < 8; ++nt) {
            half8 b = *(const half8*)&Bh[(nt * 16 + m) * LDA + k0 + quad * 8];
            acc[nt] = __builtin_amdgcn_mfma_f32_16x16x32_f16(ah, b, acc[nt], 0, 0, 0);
            acc[nt] = __builtin_amdgcn_mfma_f32_16x16x32_f16(al, b, acc[nt], 0, 0, 0);
        }
    }

    // D: row = quad*4 + reg, col = nt*16 + m
    #pragma unroll
    for (int reg = 0; reg < 4; ++reg) {
        const int row = row0 + wave * 16 + quad * 4 + reg;
        if (row < nrows) {
            const float nr = norm[row];
            #pragma unroll
            for (int nt = 0; nt < 8; ++nt)
                Hout[(size_t)row * 128 + nt * 16 + m] = __float2half(acc[nt][reg] * nr);
        }
    }
}

// Fused layer-1 aggregation + layer-2 GEMM, balanced static per-wave ranges.
// Grid = 1024 blocks x 512 thr (8192 waves, full residency). Wave gw owns
// dsts [gw*n/8192, (gw+1)*n/8192) — 12-13 dsts — processed in <=8-dst
// batches: gather batch into own LDS strip -> wave-local MFMA -> store.
// #pragma unroll 1 + sched_barrier(0) pin the phases so the compiler cannot
// software-pipeline batch k+1's gather over batch k's MFMA (R18 did that,
// spilled past the 64-VGPR cap, and the spill-fill round-tripped ~115 MB
// through HBM).
__global__ __launch_bounds__(512, 8) void gather_relu_gemm64(
    const int* __restrict__ rowptr, const int* __restrict__ csr,
    const float* __restrict__ norm, const __half* __restrict__ h,
    const float* __restrict__ bias, const __half* __restrict__ W2h,
    __half* __restrict__ h2, int n)
{
    __shared__ _Float16 Ah[72 * LDA];   // 64 data rows + 8 pad (wave 7 A-read overrun)
    __shared__ _Float16 Bh[64 * LDA];
    const int t = threadIdx.x;
    const int lane = t & 63, wave = t >> 6;
    const __half2* hp = (const __half2*)h;   // row stride 64 half2 (256 B)

    {   // stage W2 [64][128] halfs = 1024 b128-chunks, 2 per thread
        const _Float16* wf = (const _Float16*)W2h;
        #pragma unroll
        for (int i = 0; i < 2; ++i) {
            const int id = i * 512 + t;
            const int nn = id >> 4, kc = id & 15;
            *(half8*)&Bh[nn * LDA + kc * 8] = *(const half8*)&wf[nn * 128 + kc * 8];
        }
    }
    __syncthreads();   // only barrier: Bh ready for all waves

    const float bx = bias[2 * lane], by = bias[2 * lane + 1];
    const int m = lane & 15, quad = lane >> 4;

    const int gw = blockIdx.x * 8 + wave;                       // 0..8191
    const int start = (int)(((long long)gw * n) >> 13);         // gw*n/8192
    const int end   = (int)(((long long)(gw + 1) * n) >> 13);

    #pragma unroll 1
    for (int d0 = start; d0 < end; d0 += 8) {
        const int cnt = (end - d0 < 8) ? (end - d0) : 8;

        #pragma unroll 1
        for (int i = 0; i < cnt; ++i) {
            const int d = __builtin_amdgcn_readfirstlane(d0 + i);
            const int jb = rowptr[d], je = rowptr[d + 1];
            float ax[8] = {}, ay[8] = {};
            int j = jb;
            if (j + 8 <= je) {
                int s[8];
                #pragma unroll
                for (int q = 0; q < 8; ++q) s[q] = csr[j + q];
                for (; j + 16 <= je; j += 8) {
                    int sn[8];
                    #pragma unroll
                    for (int q = 0; q < 8; ++q) sn[q] = csr[j + 8 + q];
                    #pragma unroll
                    for (int q = 0; q < 8; ++q) {
                        const float2 v = __half22float2(hp[(size_t)s[q] * 64 + lane]);
                        ax[q] += v.x; ay[q] += v.y;
                    }
                    #pragma unroll
                    for (int q = 0; q < 8; ++q) s[q] = sn[q];
                }
                #pragma unroll
                for (int q = 0; q < 8; ++q) {
                    const float2 v = __half22float2(hp[(size_t)s[q] * 64 + lane]);
                    ax[q] += v.x; ay[q] += v.y;
                }
                j += 8;
            }
            for (; j < je; ++j) {
                const float2 v = __half22float2(hp[(size_t)csr[j] * 64 + lane]);
                ax[0] += v.x; ay[0] += v.y;
            }

            const float2 sv = __half22float2(hp[(size_t)d * 64 + lane]);  // self (premult)
            const float nd = norm[d];
            float sx = ((ax[0] + ax[1]) + (ax[2] + ax[3])) + ((ax[4] + ax[5]) + (ax[6] + ax[7])) + sv.x;
            float sy = ((ay[0] + ay[1]) + (ay[2] + ay[3])) + ((ay[4] + ay[5]) + (ay[6] + ay[7])) + sv.y;
            const float ox = fmaxf(fmaf(nd, sx, bx), 0.f);
            const float oy = fmaxf(fmaf(nd, sy, by), 0.f);
            ((__half2*)Ah)[((wave << 3) + i) * (LDA / 2) + lane] = __floats2half2_rn(ox, oy);
        }

        __builtin_amdgcn_sched_barrier(0);   // gather regs dead before MFMA

        // Wave-local gemm: D rows 0..cnt-1 valid, rest garbage (discarded).
        const int arow = (wave << 3) + m;   // m >= cnt reads stale/neighbor strip

        floatx4 acc[4];
        #pragma unroll
        for (int nt = 0; nt < 4; ++nt) acc[nt] = (floatx4){0.f, 0.f, 0.f, 0.f};

        #pragma unroll
        for (int k0 = 0; k0 < 128; k0 += 32) {
            half8 ah = *(const half8*)&Ah[arow * LDA + k0 + quad * 8];
            #pragma unroll
            for (int nt = 0; nt < 4; ++nt) {
                half8 b = *(const half8*)&Bh[(nt * 16 + m) * LDA + k0 + quad * 8];
                acc[nt] = __builtin_amdgcn_mfma_f32_16x16x32_f16(ah, b, acc[nt], 0, 0, 0);
            }
        }

        __builtin_amdgcn_sched_barrier(0);   // MFMA done before store/next batch

        // D: row = quad*4 + reg (keep < cnt), col = nt*16 + m
        #pragma unroll
        for (int reg = 0; reg < 4; ++reg) {
            const int rl = quad * 4 + reg;
            if (rl < cnt) {
                const int row = d0 + rl;
                const float nr = norm[row];
                #pragma unroll
                for (int nt = 0; nt < 4; ++nt)
                    h2[(size_t)row * 64 + nt * 16 + m] = __float2half(acc[nt][reg] * nr);
            }
        }
    }
}

// Layer-2 aggregation + row softmax, TWO DSTS PER WAVE: half-wave hw owns
// dst 2p+hw; its 32 lanes read the 128 B h2 row as half2 (one wave-instr
// covers both half-waves' rows = 256 B, 8-deep = 2 KB in flight vs 1 KB for
// the old scalar-fp16 form). Reductions via __shfl_xor offsets <=16 stay
// within each 32-lane half. Output: coalesced float2 (256 B per dst).
__global__ __launch_bounds__(256) void gather_softmax(
    const int* __restrict__ rowptr, const int* __restrict__ csr,
    const float* __restrict__ norm, const __half* __restrict__ h,
    const float* __restrict__ bias, float* __restrict__ out, int n)
{
    const int t = threadIdx.x;
    const int lane = t & 63;
    const int cl = lane & 31;                               // half2 col 0..31
    const int d = blockIdx.x * 8 + ((t >> 6) << 1) + (lane >> 5);
    if (d >= n) return;
    const __half2* hp = (const __half2*)h;                  // row stride 32 half2 (128 B)

    const int jb = rowptr[d], je = rowptr[d + 1];
    float ax[8] = {}, ay[8] = {};
    int j = jb;
    if (j + 8 <= je) {
        int s[8];
        #pragma unroll
        for (int q = 0; q < 8; ++q) s[q] = csr[j + q];
        for (; j + 16 <= je; j += 8) {
            int sn[8];
            #pragma unroll
            for (int q = 0; q < 8; ++q) sn[q] = csr[j + 8 + q];
            #pragma unroll
            for (int q = 0; q < 8; ++q) {
                const float2 v = __half22float2(hp[(size_t)s[q] * 32 + cl]);
                ax[q] += v.x; ay[q] += v.y;
            }
            #pragma unroll
            for (int q = 0; q < 8; ++q) s[q] = sn[q];
        }
        #pragma unroll
        for (int q = 0; q < 8; ++q) {
            const float2 v = __half22float2(hp[(size_t)s[q] * 32 + cl]);
            ax[q] += v.x; ay[q] += v.y;
        }
        j += 8;
    }
    for (; j < je; ++j) {
        const float2 v = __half22float2(hp[(size_t)csr[j] * 32 + cl]);
        ax[0] += v.x; ay[0] += v.y;
    }

    const float2 sv = __half22float2(hp[(size_t)d * 32 + cl]);   // self (premult)
    const float nd = norm[d];
    float sx = ((ax[0] + ax[1]) + (ax[2] + ax[3])) + ((ax[4] + ax[5]) + (ax[6] + ax[7])) + sv.x;
    float sy = ((ay[0] + ay[1]) + (ay[2] + ay[3])) + ((ay[4] + ay[5]) + (ay[6] + ay[7])) + sv.y;
    const float a_x = fmaf(nd, sx, bias[2 * cl]);
    const float a_y = fmaf(nd, sy, bias[2 * cl + 1]);

    float m = fmaxf(a_x, a_y);
    #pragma unroll
    for (int off = 16; off; off >>= 1) m = fmaxf(m, __shfl_xor(m, off, 64));
    const float ex = expf(a_x - m), ey = expf(a_y - m);
    float ss = ex + ey;
    #pragma unroll
    for (int off = 16; off; off >>= 1) ss += __shfl_xor(ss, off, 64);
    const float inv = 1.f / ss;
    float2 o2; o2.x = ex * inv; o2.y = ey * inv;
    *(float2*)&out[(size_t)d * 64 + 2 * cl] = o2;
}

extern "C" void kernel_launch(void* const* d_in, const int* in_sizes, int n_in,
                              void* d_out, int out_size, void* d_ws, size_t ws_size,
                              hipStream_t stream) {
    const float* x  = (const float*)d_in[0];
    const int*   ei = (const int*)d_in[1];
    const float* W1 = (const float*)d_in[2];
    const float* b1 = (const float*)d_in[3];
    const float* W2 = (const float*)d_in[4];
    const float* b2 = (const float*)d_in[5];
    float* out = (float*)d_out;

    const int N = in_sizes[0] / K_DIM;     // 100000 (<= 2^17 required)
    const int E = in_sizes[1] / 2;         // 1600000
    const int NBUCK = (N + 1023) >> 10;    // 98 buckets of 1024 nodes

    // Workspace layout (peak ~65 MB)
    size_t o = 0;
    char* base = (char*)d_ws;
    auto alloc = [&](size_t elems) {       // elems in 4-byte units
        void* p = base + o;
        o += (elems * 4 + 1023) & ~(size_t)1023;
        return p;
    };
    int*    bcount = (int*)   alloc(NB_MAX);
    int*    bbase  = (int*)   alloc(NB_MAX + 1);
    int*    bcur   = (int*)   alloc(NB_MAX);
    int*    rowptr = (int*)   alloc(N + 1);
    float*  norm   = (float*) alloc(N);
    int*    packed = (int*)   alloc(E);
    int*    csr    = (int*)   alloc(E);
    __half* W1h    = (__half*)alloc(128 * 128 / 2);
    __half* W2h    = (__half*)alloc(64 * 128 / 2);
    __half* h1h    = (__half*)alloc((size_t)N * 64);  // fp16 [Nx128]
    __half* h2h    = (__half*)alloc((size_t)N * 32);  // fp16 [Nx64]

    const int nb_c = (E + PART_CHUNK - 1) / PART_CHUNK;   // partition chunks
    const int nb_g2 = (N + 7) / 8;                        // softmax: 8 dsts/block
    const int nb_m = (N + 63) / 64;

    // ---- CSR build (two-level partition) + weight prep ----
    hipMemsetAsync(bcount, 0, NB_MAX * sizeof(int), stream);
    prep_weights<<<96, 256, 0, stream>>>(W1, W2, W1h, W2h);
    hist_buckets<<<nb_c, 256, 0, stream>>>(ei + E, E, bcount);
    scan_buckets<<<1, 64, 0, stream>>>(bcount, bbase, bcur, rowptr, N, E);
    partition_edges<<<nb_c, 256, 0, stream>>>(ei, E, bcur, packed);
    build_csr<<<NBUCK, 1024, 0, stream>>>(packed, bbase, N, rowptr, norm, csr);

    // ---- Layer 1: h1' = norm .* (x@W1), fp16 [N x 128], MFMA split-A ----
    gemm128_mfma<<<nb_m, 256, 0, stream>>>(x, W1h, norm, h1h, N);

    // ---- Fused: agg1 = relu(gather(h1')) in LDS; h2' = norm .* (agg1@W2) ----
    gather_relu_gemm64<<<1024, 512, 0, stream>>>(rowptr, csr, norm, h1h, b1, W2h, h2h, N);

    // ---- Layer 2 aggregation + softmax ----
    gather_softmax<<<nb_g2, 256, 0, stream>>>(rowptr, csr, norm, h2h, b2, out, N);
}